// Round 5
// baseline (847.903 us; speedup 1.0000x reference)
//
#include <hip/hip_runtime.h>

#define AS1 __attribute__((address_space(1)))
#define AS3 __attribute__((address_space(3)))

using u16 = unsigned short;
using u32 = unsigned int;
typedef __attribute__((ext_vector_type(8))) short bf16x8;
typedef __attribute__((ext_vector_type(4))) float f32x4;

constexpr int Bn    = 32;
constexpr int Tn    = 16384;
constexpr int TCn   = 16364;   // Tn - (K-1)
constexpr int TILE  = 256;     // conv block t-tile (64 tiles exactly)
constexpr int XROWS = 280;     // staged rows per conv block (TILE + 20 taps, chunk-rounded)
constexpr int TPAD  = 16416;   // Tn + 32 zero pad rows (16128 + 280 = 16408 <= 16416)

__device__ __forceinline__ u16 f2bf(float f) {
  union { float f; u32 u; } v; v.f = f;
  u32 u = v.u;
  u += 0x7fffu + ((u >> 16) & 1u);   // RNE
  return (u16)(u >> 16);
}
__device__ __forceinline__ float bf2f(u32 h) {
  union { u32 u; float f; } v; v.u = h << 16; return v.f;
}
// order-preserving float<->uint for atomicMax on signed floats (all reals map > 0)
__device__ __forceinline__ u32 encf(float f) {
  union { float f; u32 u; } v; v.f = f;
  return (v.u & 0x80000000u) ? ~v.u : (v.u | 0x80000000u);
}
__device__ __forceinline__ float decf(u32 u) {
  union { u32 u; float f; } v;
  v.u = (u & 0x80000000u) ? (u ^ 0x80000000u) : ~u;
  return v.f;
}
__device__ __forceinline__ void gload_lds16(const void* g, void* l) {
  // per-lane 16B global -> (wave-uniform LDS base + lane*16)
  __builtin_amdgcn_global_load_lds((const AS1 u32*)g, (AS3 u32*)l, 16, 0, 0);
}
__device__ __forceinline__ float leaky(float z) { return z > 0.f ? z : 0.01f * z; }

// ---------------------------------------------------------------------------
// Kernel 1: (a) x (B,C,T) fp32 -> x_t[b][t][ci ^ ((t&7)*8)] bf16 + zero pad;
//           (b) tail blocks repack weights into MFMA A-fragment order.
// LDS: write PLAIN lt[tl][ci] (packed b64, 4-way conflict, cheap); readback
// applies the XOR swizzle to the LDS index and stores to plain x_t offset:
//   x_t[t][c] = lt[t][c ^ (t&7)*8] = value(ci = c ^ (t&7)*8)  -- the swizzled
// layout conv_mfma expects. (Round-4 bug: swizzle applied on BOTH sides
// cancelled out -> unswizzled x_t -> wrong channel pairing in conv.)
// ---------------------------------------------------------------------------
__global__ __launch_bounds__(256) void transpose_x(const float* __restrict__ x,
                                                   u16* __restrict__ x_t,
                                                   const float* __restrict__ w1,
                                                   const float* __restrict__ w2,
                                                   u16* __restrict__ wf1,
                                                   u16* __restrict__ wf2) {
  __shared__ u16 lt[64][64];               // 8 KB, [t][ci] (plain)
  const int bx  = blockIdx.x;
  const int tid = threadIdx.x;

  if (bx >= Bn * 256) {                    // ---- weight repack (84 blocks) ----
    const int bxx = bx - Bn * 256;
    const int cv  = bxx / 42;
    const int c   = bxx % 42;
    const float* w = cv ? w2 : w1;
    u16* wf = cv ? wf2 : wf1;
    const int ct   = tid >> 6;
    const int lane = tid & 63;
    const int q  = lane >> 4;
    const int rr = lane & 15;
    const int k  = c >> 1;
    const int cb = (c & 1) * 32;
    const int co = ct * 16 + rr;
    u16 us[8] __attribute__((aligned(16)));
#pragma unroll
    for (int j = 0; j < 8; ++j) {
      int ci = cb + q * 8 + j;
      us[j] = f2bf(w[((size_t)co * 64 + ci) * 21 + k]);
    }
    *(uint4*)&wf[((size_t)(c * 4 + ct) * 64 + lane) * 8] = *(const uint4*)us;
    return;
  }

  const int b   = bx >> 8;
  const int tt  = bx & 255;
  const int t0  = tt * 64;
  const int ci0 = (tid & 15) * 4;
  const int tl0 = (tid >> 4) * 4;
  float4 v[4];
#pragma unroll
  for (int j = 0; j < 4; ++j)
    v[j] = *(const float4*)(x + (size_t)(b * 64 + ci0 + j) * Tn + t0 + tl0);
  float vr[4][4] = {{v[0].x,v[0].y,v[0].z,v[0].w},{v[1].x,v[1].y,v[1].z,v[1].w},
                    {v[2].x,v[2].y,v[2].z,v[2].w},{v[3].x,v[3].y,v[3].z,v[3].w}};
#pragma unroll
  for (int e = 0; e < 4; ++e) {
    int tl = tl0 + e;
    u32 lo = (u32)f2bf(vr[0][e]) | ((u32)f2bf(vr[1][e]) << 16);
    u32 hi = (u32)f2bf(vr[2][e]) | ((u32)f2bf(vr[3][e]) << 16);
    uint2 pk = make_uint2(lo, hi);
    *(uint2*)&lt[tl][ci0] = pk;              // ds_write_b64, PLAIN index
  }
  __syncthreads();
  const int row = tid >> 2;
  const int seg = tid & 3;
  const int c0  = seg * 16;
  const int sw  = (row & 7) * 8;
  u16* op = x_t + ((size_t)b * TPAD + t0 + row) * 64 + c0;
  *(uint4*)op       = *(const uint4*)&lt[row][c0 ^ sw];        // swizzle on READ
  *(uint4*)(op + 8) = *(const uint4*)&lt[row][(c0 + 8) ^ sw];
  if (tt == 0) {  // zero the 32 pad rows: 32*64 u16 = 4096B = 256 x 16B
    uint4 z = make_uint4(0u, 0u, 0u, 0u);
    uint4* pz = (uint4*)(x_t + ((size_t)b * TPAD + Tn) * 64);
    pz[tid] = z;
  }
}

// ---------------------------------------------------------------------------
// Kernel 2: implicit-GEMM conv via mfma_f32_16x16x32_bf16, both convs.
// ROUND-1 PROVEN STRUCTURE: 2-barrier K-loop, weights staged to LDS in 6
// groups of 7 chunks via global_load_lds; xs 280 rows; 65024 B LDS ->
// 2 blocks/CU (21.7% occ, MfmaUtil 37% measured).
// Epilogue (proven round 2): cv=0 fused raw max/min pool, NO y store;
// cv=1 swizzled-LDS-transposed y2 store. Both: BN sum/sumsq.
// ---------------------------------------------------------------------------
__global__ __launch_bounds__(256, 2) void conv_mfma(const u16* __restrict__ x_t,
                                                    const u16* __restrict__ wf1,
                                                    const u16* __restrict__ wf2,
                                                    u16* __restrict__ y2,
                                                    float* __restrict__ stats,
                                                    u32* __restrict__ mm,
                                                    const int* __restrict__ orig_len) {
  __shared__ u16 xs[XROWS * 64];       // 35840 B
  __shared__ u16 wsw[7 * 4 * 64 * 8];  // 28672 B
  __shared__ float sred[128];          // 512 B   -> total 65024 B

  const int bid  = blockIdx.x;
  const int cv   = bid & 1;
  const int tmp  = bid >> 1;
  const int tile = tmp & 63;
  const int b    = tmp >> 6;
  const int t0   = tile * TILE;
  const int tid  = threadIdx.x;
  const int w    = tid >> 6;    // wave id
  const int lane = tid & 63;
  const int q    = lane >> 4;
  const int r    = lane & 15;
  const u16* wf  = cv ? wf2 : wf1;

  if (tid < 128) sred[tid] = 0.f;

  // stage x tile: 280 rows * 128B = 35 x 1KB chunks
  const u16* xg = x_t + ((size_t)b * TPAD + t0) * 64;
  for (int s = w; s < 35; s += 4)
    gload_lds16(xg + (size_t)s * 512 + lane * 8, &xs[s * 512]);

  f32x4 acc[4][4];
#pragma unroll
  for (int a = 0; a < 4; ++a)
#pragma unroll
    for (int t = 0; t < 4; ++t)
      acc[a][t] = (f32x4){0.f, 0.f, 0.f, 0.f};

  for (int g = 0; g < 6; ++g) {
    // stage weight group g (7 chunks = 28KB = 28 x 1KB)
    const u16* wg = wf + (size_t)g * 14336;
    for (int s = w; s < 28; s += 4)
      gload_lds16(wg + (size_t)s * 512 + lane * 8, &wsw[s * 512]);
    __syncthreads();   // staging (and, for g=0, x tile) visible
#pragma unroll
    for (int cl = 0; cl < 7; ++cl) {
      const int c  = g * 7 + cl;
      const int k  = c >> 1;
      const int cb = (c & 1) * 32;
      bf16x8 af[4];
#pragma unroll
      for (int ct = 0; ct < 4; ++ct)
        af[ct] = *(const bf16x8*)&wsw[((cl * 4 + ct) * 64 + lane) * 8];
      bf16x8 bx[4];
#pragma unroll
      for (int tt = 0; tt < 4; ++tt) {
        int p = w * 64 + tt * 16 + r + k;
        int cidx = (cb + q * 8) ^ ((p & 7) * 8);   // bake the x_t XOR swizzle
        bx[tt] = *(const bf16x8*)&xs[p * 64 + cidx];
      }
#pragma unroll
      for (int ct = 0; ct < 4; ++ct)
#pragma unroll
        for (int tt = 0; tt < 4; ++tt)
          acc[ct][tt] = __builtin_amdgcn_mfma_f32_16x16x32_bf16(af[ct], bx[tt], acc[ct][tt], 0, 0, 0);
    }
    __syncthreads();   // group's reads done before next staging / epilogue LDS reuse
  }

  // ---- BN statistics (mask t >= TC) ----
#pragma unroll
  for (int ct = 0; ct < 4; ++ct)
#pragma unroll
    for (int i = 0; i < 4; ++i) {
      float sv = 0.f, sq = 0.f;
#pragma unroll
      for (int tt = 0; tt < 4; ++tt) {
        int tg = t0 + w * 64 + tt * 16 + r;
        if (tg < TCn) {
          float v = acc[ct][tt][i];
          sv += v; sq += v * v;
        }
      }
#pragma unroll
      for (int m = 1; m < 16; m <<= 1) {
        sv += __shfl_xor(sv, m, 64);
        sq += __shfl_xor(sq, m, 64);
      }
      if (r == 0) {
        int co = ct * 16 + q * 4 + i;
        atomicAdd(&sred[co * 2], sv);
        atomicAdd(&sred[co * 2 + 1], sq);
      }
    }
  __syncthreads();   // sred complete; all xs K-loop reads done before ys reuse

  if (cv == 0) {
    // ---- fused max-pool: per-(b,co,bin) raw max & min over this block's t ----
    const int L     = orig_len[b] - 20;
    const int str2  = L >> 1;
    const int kern2 = L - str2;
#pragma unroll
    for (int ct = 0; ct < 4; ++ct)
#pragma unroll
      for (int i = 0; i < 4; ++i) {
        float mx0 = -3.4e38f, mn0 = 3.4e38f, mx1 = -3.4e38f, mn1 = 3.4e38f;
#pragma unroll
        for (int tt = 0; tt < 4; ++tt) {
          int tg = t0 + w * 64 + tt * 16 + r;
          float v = acc[ct][tt][i];
          if (tg < kern2)            { mx0 = fmaxf(mx0, v); mn0 = fminf(mn0, v); }
          if (tg >= str2 && tg < L)  { mx1 = fmaxf(mx1, v); mn1 = fminf(mn1, v); }
        }
#pragma unroll
        for (int m = 1; m < 16; m <<= 1) {
          mx0 = fmaxf(mx0, __shfl_xor(mx0, m, 64));
          mn0 = fminf(mn0, __shfl_xor(mn0, m, 64));
          mx1 = fmaxf(mx1, __shfl_xor(mx1, m, 64));
          mn1 = fminf(mn1, __shfl_xor(mn1, m, 64));
        }
        if (r == 0) {
          int co = ct * 16 + q * 4 + i;
          u32* p = &mm[((size_t)b * 64 + co) * 4];
          atomicMax(&p[0], encf(mx0));
          atomicMax(&p[1], encf(-mn0));   // -min via max of negation
          atomicMax(&p[2], encf(mx1));
          atomicMax(&p[3], encf(-mn1));
        }
      }
  } else {
    // ---- store y2[b][t][co] bf16 via swizzled LDS transpose (reuse xs) ----
    u16* ys = xs;   // 256*64 u16 = 32768 B <= 35840 B
#pragma unroll
    for (int ct = 0; ct < 4; ++ct)
#pragma unroll
      for (int tt = 0; tt < 4; ++tt) {
        int tl = w * 64 + tt * 16 + r;
#pragma unroll
        for (int ip = 0; ip < 2; ++ip) {
          int co = ct * 16 + q * 4 + ip * 2;             // even
          u32 val = (u32)f2bf(acc[ct][tt][ip * 2]) |
                    ((u32)f2bf(acc[ct][tt][ip * 2 + 1]) << 16);
          int col = co ^ ((r & 7) * 8);                  // swizzle breaks bank aliasing
          *(u32*)&ys[tl * 64 + col] = val;
        }
      }
    __syncthreads();
    u16* yo = y2 + ((size_t)b * Tn + t0) * 64;
#pragma unroll
    for (int m = 0; m < 8; ++m) {                        // 16B units, coalesced
      int u = m * 256 + tid;
      int row = u >> 3, c0 = (u & 7) * 8;
      int col = c0 ^ ((row & 7) * 8);
      *(uint4*)(yo + (size_t)row * 64 + c0) = *(const uint4*)&ys[row * 64 + col];
    }
  }
  if (tid < 128) atomicAdd(&stats[cv * 128 + tid], sred[tid]);
}

// ---------------------------------------------------------------------------
// Kernel 3: SPP avg path on y2. BN affine (a,c) recomputed inline from stats
// (replaces the bn_finalize launch). Thread: 4 co x t-row, uint2 loads.
// ---------------------------------------------------------------------------
__global__ __launch_bounds__(256) void spp(const u16* __restrict__ y2,
                                           const float* __restrict__ stats,
                                           const float* __restrict__ g2,
                                           const float* __restrict__ b2,
                                           const int* __restrict__ orig_len,
                                           float* __restrict__ feat) {
  const int bx = blockIdx.x;
  const int b  = bx >> 4;
  const int ch = bx & 15;
  const int tid  = threadIdx.x;
  const int g    = tid & 15;       // co group: co = g*4 .. g*4+3
  const int trow = tid >> 4;       // 0..15
  const int co0  = g * 4;
  const int L     = orig_len[b] - 20;
  const int str2  = L >> 1;
  const int kern2 = L - str2;
  const float Nf = 32.0f * 16364.0f;
  float a2[4], c2[4];
#pragma unroll
  for (int j = 0; j < 4; ++j) {
    int co = co0 + j;
    float s  = stats[128 + co * 2];
    float sq = stats[128 + co * 2 + 1];
    float mean = s / Nf;
    float var  = sq / Nf - mean * mean;
    if (var < 0.f) var = 0.f;
    a2[j] = g2[co] * rsqrtf(var + 1e-5f);
    c2[j] = b2[co] - mean * a2[j];
  }
  float s0[4] = {0,0,0,0}, sb0[4] = {0,0,0,0}, sb1[4] = {0,0,0,0};
  const int tbase = ch * 1024;
  int tend = tbase + 1024;
  if (tend > L) tend = L;
  const u16* p2 = y2 + (size_t)b * Tn * 64 + co0;
  for (int t = tbase + trow; t < tend; t += 16) {
    uint2 v = *(const uint2*)(p2 + (size_t)t * 64);
    float f[4] = { bf2f(v.x & 0xffffu), bf2f(v.x >> 16),
                   bf2f(v.y & 0xffffu), bf2f(v.y >> 16) };
    bool in0 = (t < kern2), in1 = (t >= str2);
#pragma unroll
    for (int j = 0; j < 4; ++j) {
      float z = leaky(fmaf(a2[j], f[j], c2[j]));
      s0[j] += z;
      if (in0) sb0[j] += z;
      if (in1) sb1[j] += z;
    }
  }
#pragma unroll
  for (int m = 16; m <= 32; m <<= 1) {
#pragma unroll
    for (int j = 0; j < 4; ++j) {
      s0[j]  += __shfl_xor(s0[j],  m, 64);
      sb0[j] += __shfl_xor(sb0[j], m, 64);
      sb1[j] += __shfl_xor(sb1[j], m, 64);
    }
  }
  if (((tid & 63) >> 4) == 0) {
    float* fb = feat + (size_t)b * 384;
#pragma unroll
    for (int j = 0; j < 4; ++j) {
      int co = co0 + j;
      atomicAdd(&fb[192 + co], s0[j]);
      atomicAdd(&fb[256 + co * 2], sb0[j]);
      atomicAdd(&fb[256 + co * 2 + 1], sb1[j]);
    }
  }
}

// ---------------------------------------------------------------------------
// Kernel 4: FC. Decodes the max-pool (mm) inline with cv=0 BN affine computed
// from stats (absorbs bn_finalize), scales avg sums, dots with fc_w.
// ---------------------------------------------------------------------------
__global__ void fc(const float* __restrict__ stats,
                   const float* __restrict__ g1v, const float* __restrict__ b1v,
                   const u32* __restrict__ mm,
                   const float* __restrict__ feat,
                   const int* __restrict__ orig_len,
                   const float* __restrict__ fc_w,
                   const float* __restrict__ fc_b,
                   float* __restrict__ out) {
  __shared__ float sab[128];
  const int tid = threadIdx.x;        // 256
  if (tid < 64) {
    const float Nf = 32.0f * 16364.0f;
    float s  = stats[tid * 2];
    float sq = stats[tid * 2 + 1];
    float mean = s / Nf;
    float var  = sq / Nf - mean * mean;
    if (var < 0.f) var = 0.f;
    float a = g1v[tid] * rsqrtf(var + 1e-5f);
    sab[tid * 2]     = a;
    sab[tid * 2 + 1] = b1v[tid] - mean * a;
  }
  __syncthreads();
  const int pair = tid >> 2;           // (b,n)
  const int part = tid & 3;
  const int b = pair >> 1;
  const int n = pair & 1;
  const int L = orig_len[b] - 20;
  const int kern2 = L - (L >> 1);
  const float* ff = feat + (size_t)b * 384;
  float acc = 0.f;
  for (int j = part; j < 384; j += 4) {
    float fv;
    if (j < 192) {
      int co, bin;                     // bin: 0=whole, 1=bin0, 2=bin1
      if (j < 64) { co = j; bin = 0; }
      else        { co = (j - 64) >> 1; bin = 1 + ((j - 64) & 1); }
      const u32* p = &mm[((size_t)b * 64 + co) * 4];
      float a = sab[co * 2], c = sab[co * 2 + 1];
      float v;
      if (a >= 0.f) {
        float mx0 = decf(p[0]), mx1 = decf(p[2]);
        v = (bin == 0) ? fmaxf(mx0, mx1) : (bin == 1 ? mx0 : mx1);
      } else {
        float mn0 = -decf(p[1]), mn1 = -decf(p[3]);
        v = (bin == 0) ? fminf(mn0, mn1) : (bin == 1 ? mn0 : mn1);
      }
      fv = leaky(fmaf(a, v, c));
    } else if (j < 256) {
      fv = ff[j] / (float)L;
    } else {
      fv = ff[j] / (float)kern2;
    }
    acc += fv * fc_w[n * 384 + j];
  }
  acc += __shfl_xor(acc, 1, 64);
  acc += __shfl_xor(acc, 2, 64);
  if (part == 0) out[b * 2 + n] = acc + fc_b[n];
}

// ---------------------------------------------------------------------------
extern "C" void kernel_launch(void* const* d_in, const int* in_sizes, int n_in,
                              void* d_out, int out_size, void* d_ws, size_t ws_size,
                              hipStream_t stream) {
  const float* x        = (const float*)d_in[0];
  const int*   orig_len = (const int*)d_in[1];
  const float* w1  = (const float*)d_in[2];
  const float* g1  = (const float*)d_in[3];
  const float* b1  = (const float*)d_in[4];
  const float* w2  = (const float*)d_in[5];
  const float* g2  = (const float*)d_in[6];
  const float* b2  = (const float*)d_in[7];
  const float* fcw = (const float*)d_in[8];
  const float* fcb = (const float*)d_in[9];
  float* out = (float*)d_out;

  char* ws = (char*)d_ws;
  const size_t XT_BYTES = (size_t)Bn * TPAD * 64 * 2;    // 67,239,936
  const size_t Y_BYTES  = (size_t)Bn * Tn * 64 * 2;      // 67,108,864
  const size_t WF_BYTES = (size_t)42 * 4 * 64 * 8 * 2;   // 172,032
  size_t off = 0;
  u16* x_t = (u16*)(ws + off); off += XT_BYTES;
  u16* y2  = (u16*)(ws + off); off += Y_BYTES;
  u16* wf1 = (u16*)(ws + off); off += WF_BYTES;
  u16* wf2 = (u16*)(ws + off); off += WF_BYTES;
  float* stats = (float*)(ws + off);                 // 1024 B (2cv x 64co x {s,sq})
  float* feat  = (float*)(ws + off + 1024);          // 32*384*4 = 49152 B
  u32*   mm    = (u32*)(ws + off + 1024 + 49152);    // 32*64*4*4 = 32768 B
  const size_t SMALL_BYTES = 1024 + 49152 + 32768;

  hipMemsetAsync(ws + off, 0, SMALL_BYTES, stream);
  transpose_x<<<Bn * 256 + 84, 256, 0, stream>>>(x, x_t, w1, w2, wf1, wf2);
  conv_mfma<<<Bn * 64 * 2, 256, 0, stream>>>(x_t, wf1, wf2, y2, stats, mm, orig_len);
  spp<<<Bn * 16, 256, 0, stream>>>(y2, stats, g2, b2, orig_len, feat);
  fc<<<1, 256, 0, stream>>>(stats, g1, b1, mm, feat, orig_len, fcw, fcb, out);
  (void)in_sizes; (void)n_in; (void)out_size; (void)ws_size;
}

// Round 6
// 489.575 us; speedup vs baseline: 1.7319x; 1.7319x over previous
//
#include <hip/hip_runtime.h>

#define AS1 __attribute__((address_space(1)))
#define AS3 __attribute__((address_space(3)))

using u16 = unsigned short;
using u32 = unsigned int;
typedef __attribute__((ext_vector_type(8))) short bf16x8;
typedef __attribute__((ext_vector_type(4))) float f32x4;

constexpr int Bn    = 32;
constexpr int Tn    = 16384;
constexpr int TCn   = 16364;   // Tn - (K-1)
constexpr int TILE  = 256;     // conv block t-tile (64 tiles exactly)
constexpr int XROWS = 280;     // staged rows per conv block
constexpr int TPAD  = 16416;   // Tn + 32 zero pad rows

__device__ __forceinline__ u16 f2bf(float f) {
  union { float f; u32 u; } v; v.f = f;
  u32 u = v.u;
  u += 0x7fffu + ((u >> 16) & 1u);   // RNE
  return (u16)(u >> 16);
}
__device__ __forceinline__ float bf2f(u32 h) {
  union { u32 u; float f; } v; v.u = h << 16; return v.f;
}
// order-preserving float<->uint for atomicMax on signed floats (all reals map > 0)
__device__ __forceinline__ u32 encf(float f) {
  union { float f; u32 u; } v; v.f = f;
  return (v.u & 0x80000000u) ? ~v.u : (v.u | 0x80000000u);
}
__device__ __forceinline__ float decf(u32 u) {
  union { u32 u; float f; } v;
  v.u = (u & 0x80000000u) ? (u ^ 0x80000000u) : ~u;
  return v.f;
}
__device__ __forceinline__ void gload_lds16(const void* g, void* l) {
  __builtin_amdgcn_global_load_lds((const AS1 u32*)g, (AS3 u32*)l, 16, 0, 0);
}
__device__ __forceinline__ float leaky(float z) { return z > 0.f ? z : 0.01f * z; }

// ---------------------------------------------------------------------------
// Kernel 1: (a) x -> x_t[b][t][ci ^ ((t&7)*8)] bf16 + zero pad (b64 LDS writes,
// swizzle applied on LDS read — verified correct in round 5);
// (b) tail blocks repack weights into MFMA A-fragment order.
// ---------------------------------------------------------------------------
__global__ __launch_bounds__(256) void transpose_x(const float* __restrict__ x,
                                                   u16* __restrict__ x_t,
                                                   const float* __restrict__ w1,
                                                   const float* __restrict__ w2,
                                                   u16* __restrict__ wf1,
                                                   u16* __restrict__ wf2) {
  __shared__ u16 lt[64][64];               // 8 KB, [t][ci] (plain)
  const int bx  = blockIdx.x;
  const int tid = threadIdx.x;

  if (bx >= Bn * 256) {                    // ---- weight repack (84 blocks) ----
    const int bxx = bx - Bn * 256;
    const int cv  = bxx / 42;
    const int c   = bxx % 42;
    const float* w = cv ? w2 : w1;
    u16* wf = cv ? wf2 : wf1;
    const int ct   = tid >> 6;
    const int lane = tid & 63;
    const int q  = lane >> 4;
    const int rr = lane & 15;
    const int k  = c >> 1;
    const int cb = (c & 1) * 32;
    const int co = ct * 16 + rr;
    u16 us[8] __attribute__((aligned(16)));
#pragma unroll
    for (int j = 0; j < 8; ++j) {
      int ci = cb + q * 8 + j;
      us[j] = f2bf(w[((size_t)co * 64 + ci) * 21 + k]);
    }
    *(uint4*)&wf[((size_t)(c * 4 + ct) * 64 + lane) * 8] = *(const uint4*)us;
    return;
  }

  const int b   = bx >> 8;
  const int tt  = bx & 255;
  const int t0  = tt * 64;
  const int ci0 = (tid & 15) * 4;
  const int tl0 = (tid >> 4) * 4;
  float4 v[4];
#pragma unroll
  for (int j = 0; j < 4; ++j)
    v[j] = *(const float4*)(x + (size_t)(b * 64 + ci0 + j) * Tn + t0 + tl0);
  float vr[4][4] = {{v[0].x,v[0].y,v[0].z,v[0].w},{v[1].x,v[1].y,v[1].z,v[1].w},
                    {v[2].x,v[2].y,v[2].z,v[2].w},{v[3].x,v[3].y,v[3].z,v[3].w}};
#pragma unroll
  for (int e = 0; e < 4; ++e) {
    int tl = tl0 + e;
    u32 lo = (u32)f2bf(vr[0][e]) | ((u32)f2bf(vr[1][e]) << 16);
    u32 hi = (u32)f2bf(vr[2][e]) | ((u32)f2bf(vr[3][e]) << 16);
    uint2 pk = make_uint2(lo, hi);
    *(uint2*)&lt[tl][ci0] = pk;              // ds_write_b64, PLAIN index
  }
  __syncthreads();
  const int row = tid >> 2;
  const int seg = tid & 3;
  const int c0  = seg * 16;
  const int sw  = (row & 7) * 8;
  u16* op = x_t + ((size_t)b * TPAD + t0 + row) * 64 + c0;
  *(uint4*)op       = *(const uint4*)&lt[row][c0 ^ sw];        // swizzle on READ
  *(uint4*)(op + 8) = *(const uint4*)&lt[row][(c0 + 8) ^ sw];
  if (tt == 0) {
    uint4 z = make_uint4(0u, 0u, 0u, 0u);
    uint4* pz = (uint4*)(x_t + ((size_t)b * TPAD + Tn) * 64);
    pz[tid] = z;
  }
}

// ---------------------------------------------------------------------------
// Kernel 2: implicit-GEMM conv — BYTE-IDENTICAL to round-1's measured kernel
// (217 us, MfmaUtil 37%, occ 21.7%). 2-barrier K-loop, weights staged via
// global_load_lds in 6 groups of 7 chunks, both cv store y (plain LDS
// transpose), per-channel BN sum/sumsq. NO global atomicMax epilogue —
// that epilogue is the common factor in the 3 slow rounds (R2/R3/R5).
// ---------------------------------------------------------------------------
__global__ __launch_bounds__(256, 2) void conv_mfma(const u16* __restrict__ x_t,
                                                    const u16* __restrict__ wf1,
                                                    const u16* __restrict__ wf2,
                                                    u16* __restrict__ y1,
                                                    u16* __restrict__ y2,
                                                    float* __restrict__ stats) {
  __shared__ u16 xs[XROWS * 64];       // 35840 B
  __shared__ u16 wsw[7 * 4 * 64 * 8];  // 28672 B
  __shared__ float sred[128];          // 512 B   -> total 65024 B

  const int bid  = blockIdx.x;
  const int cv   = bid & 1;
  const int tmp  = bid >> 1;
  const int tile = tmp & 63;
  const int b    = tmp >> 6;
  const int t0   = tile * TILE;
  const int tid  = threadIdx.x;
  const int w    = tid >> 6;    // wave id
  const int lane = tid & 63;
  const int q    = lane >> 4;
  const int r    = lane & 15;
  const u16* wf  = cv ? wf2 : wf1;

  if (tid < 128) sred[tid] = 0.f;

  // stage x tile: 280 rows * 128B = 35 x 1KB chunks
  const u16* xg = x_t + ((size_t)b * TPAD + t0) * 64;
  for (int s = w; s < 35; s += 4)
    gload_lds16(xg + (size_t)s * 512 + lane * 8, &xs[s * 512]);

  f32x4 acc[4][4];
#pragma unroll
  for (int a = 0; a < 4; ++a)
#pragma unroll
    for (int t = 0; t < 4; ++t)
      acc[a][t] = (f32x4){0.f, 0.f, 0.f, 0.f};

  for (int g = 0; g < 6; ++g) {
    const u16* wg = wf + (size_t)g * 14336;
    for (int s = w; s < 28; s += 4)
      gload_lds16(wg + (size_t)s * 512 + lane * 8, &wsw[s * 512]);
    __syncthreads();   // staging (and, for g=0, x tile) visible
#pragma unroll
    for (int cl = 0; cl < 7; ++cl) {
      const int c  = g * 7 + cl;
      const int k  = c >> 1;
      const int cb = (c & 1) * 32;
      bf16x8 af[4];
#pragma unroll
      for (int ct = 0; ct < 4; ++ct)
        af[ct] = *(const bf16x8*)&wsw[((cl * 4 + ct) * 64 + lane) * 8];
      bf16x8 bx[4];
#pragma unroll
      for (int tt = 0; tt < 4; ++tt) {
        int p = w * 64 + tt * 16 + r + k;
        int cidx = (cb + q * 8) ^ ((p & 7) * 8);   // bake the x_t XOR swizzle
        bx[tt] = *(const bf16x8*)&xs[p * 64 + cidx];
      }
#pragma unroll
      for (int ct = 0; ct < 4; ++ct)
#pragma unroll
        for (int tt = 0; tt < 4; ++tt)
          acc[ct][tt] = __builtin_amdgcn_mfma_f32_16x16x32_bf16(af[ct], bx[tt], acc[ct][tt], 0, 0, 0);
    }
    __syncthreads();
  }

  // ---- BN statistics (mask t >= TC) ----
#pragma unroll
  for (int ct = 0; ct < 4; ++ct)
#pragma unroll
    for (int i = 0; i < 4; ++i) {
      float sv = 0.f, sq = 0.f;
#pragma unroll
      for (int tt = 0; tt < 4; ++tt) {
        int tg = t0 + w * 64 + tt * 16 + r;
        if (tg < TCn) {
          float v = acc[ct][tt][i];
          sv += v; sq += v * v;
        }
      }
#pragma unroll
      for (int m = 1; m < 16; m <<= 1) {
        sv += __shfl_xor(sv, m, 64);
        sq += __shfl_xor(sq, m, 64);
      }
      if (r == 0) {
        int co = ct * 16 + q * 4 + i;
        atomicAdd(&sred[co * 2], sv);
        atomicAdd(&sred[co * 2 + 1], sq);
      }
    }

  // ---- store y_t[b][t][co] bf16 via LDS transpose (reuse xs) ----
  u16* ys = xs;
#pragma unroll
  for (int ct = 0; ct < 4; ++ct)
#pragma unroll
    for (int tt = 0; tt < 4; ++tt) {
      int tl = w * 64 + tt * 16 + r;
#pragma unroll
      for (int i = 0; i < 4; ++i) {
        int co = ct * 16 + q * 4 + i;
        ys[tl * 64 + co] = f2bf(acc[ct][tt][i]);
      }
    }
  __syncthreads();
  u16* yo = (cv ? y2 : y1) + ((size_t)b * Tn + t0) * 64;
#pragma unroll
  for (int m = 0; m < 8; ++m) {
    int idx = (m * 256 + tid) * 8;
    *(uint4*)(yo + idx) = *(const uint4*)(ys + idx);
  }
  if (tid < 128) atomicAdd(&stats[cv * 128 + tid], sred[tid]);
}

// ---------------------------------------------------------------------------
// Kernel 3: SPP, both tensors, vectorized. Block = (b, 1/16th of t).
// Thread: 4 channels (uint2 loads from y1 AND y2) x 16-row stride.
// BN affine computed inline from stats (replaces bn_finalize launch).
// Shuffle-reduce across the 4 row-lanes sharing a channel group, then
// atomics to featU (same layout as round 1: enc-max [0,192), sums [192,384)).
// ---------------------------------------------------------------------------
__global__ __launch_bounds__(256) void spp(const u16* __restrict__ y1,
                                           const u16* __restrict__ y2,
                                           const float* __restrict__ stats,
                                           const float* __restrict__ g1v,
                                           const float* __restrict__ b1v,
                                           const float* __restrict__ g2v,
                                           const float* __restrict__ b2v,
                                           const int* __restrict__ orig_len,
                                           u32* __restrict__ featU) {
  const int bx = blockIdx.x;
  const int b  = bx >> 4;
  const int ch = bx & 15;
  const int tid  = threadIdx.x;
  const int g    = tid & 15;       // channel group: co = g*4 .. g*4+3
  const int trow = tid >> 4;       // 0..15
  const int co0  = g * 4;
  const int L     = orig_len[b] - 20;
  const int str2  = L >> 1;
  const int kern2 = L - str2;
  const float Nf = 32.0f * 16364.0f;
  float a1[4], c1[4], a2[4], c2[4];
#pragma unroll
  for (int j = 0; j < 4; ++j) {
    int co = co0 + j;
    float s, sq, mean, var;
    s = stats[co * 2]; sq = stats[co * 2 + 1];
    mean = s / Nf; var = sq / Nf - mean * mean; if (var < 0.f) var = 0.f;
    a1[j] = g1v[co] * rsqrtf(var + 1e-5f);
    c1[j] = b1v[co] - mean * a1[j];
    s = stats[128 + co * 2]; sq = stats[128 + co * 2 + 1];
    mean = s / Nf; var = sq / Nf - mean * mean; if (var < 0.f) var = 0.f;
    a2[j] = g2v[co] * rsqrtf(var + 1e-5f);
    c2[j] = b2v[co] - mean * a2[j];
  }
  float m1[4] = {-3.4e38f,-3.4e38f,-3.4e38f,-3.4e38f};
  float m2[4] = {-3.4e38f,-3.4e38f,-3.4e38f,-3.4e38f};
  float s0[4] = {0,0,0,0}, sb0[4] = {0,0,0,0}, sb1[4] = {0,0,0,0};
  const int tbase = ch * 1024;
  int tend = tbase + 1024;
  if (tend > L) tend = L;
  const u16* p1 = y1 + (size_t)b * Tn * 64 + co0;
  const u16* p2 = y2 + (size_t)b * Tn * 64 + co0;
  for (int t = tbase + trow; t < tend; t += 16) {
    uint2 v1 = *(const uint2*)(p1 + (size_t)t * 64);
    uint2 v2 = *(const uint2*)(p2 + (size_t)t * 64);
    float f1[4] = { bf2f(v1.x & 0xffffu), bf2f(v1.x >> 16),
                    bf2f(v1.y & 0xffffu), bf2f(v1.y >> 16) };
    float f2[4] = { bf2f(v2.x & 0xffffu), bf2f(v2.x >> 16),
                    bf2f(v2.y & 0xffffu), bf2f(v2.y >> 16) };
    bool in0 = (t < kern2), in1 = (t >= str2);   // t < L via tend
#pragma unroll
    for (int j = 0; j < 4; ++j) {
      float z1 = leaky(fmaf(a1[j], f1[j], c1[j]));
      float z2 = leaky(fmaf(a2[j], f2[j], c2[j]));
      s0[j] += z2;
      if (in0) { m1[j] = fmaxf(m1[j], z1); sb0[j] += z2; }
      if (in1) { m2[j] = fmaxf(m2[j], z1); sb1[j] += z2; }
    }
  }
  // reduce across the 4 row-lanes in this wave sharing g (lane>>4)
#pragma unroll
  for (int m = 16; m <= 32; m <<= 1) {
#pragma unroll
    for (int j = 0; j < 4; ++j) {
      m1[j]  = fmaxf(m1[j], __shfl_xor(m1[j], m, 64));
      m2[j]  = fmaxf(m2[j], __shfl_xor(m2[j], m, 64));
      s0[j]  += __shfl_xor(s0[j],  m, 64);
      sb0[j] += __shfl_xor(sb0[j], m, 64);
      sb1[j] += __shfl_xor(sb1[j], m, 64);
    }
  }
  if (((tid & 63) >> 4) == 0) {
    u32* fb = featU + (size_t)b * 384;
    float* ff = (float*)fb;
#pragma unroll
    for (int j = 0; j < 4; ++j) {
      int co = co0 + j;
      u32 e1 = encf(m1[j]), e2 = encf(m2[j]);
      atomicMax(&fb[co], e1 > e2 ? e1 : e2);   // level0 max = max(bin0,bin1)
      atomicMax(&fb[64 + co * 2], e1);
      atomicMax(&fb[64 + co * 2 + 1], e2);
      atomicAdd(&ff[192 + co], s0[j]);
      atomicAdd(&ff[256 + co * 2], sb0[j]);
      atomicAdd(&ff[256 + co * 2 + 1], sb1[j]);
    }
  }
}

// ---------------------------------------------------------------------------
// Kernel 4: FC. feat(32,384) @ fc_w^T(384,2) + fc_b. Decode maxes, scale avgs.
// (Round-1 proven version.)
// ---------------------------------------------------------------------------
__global__ void fc(const u32* __restrict__ featU,
                   const int* __restrict__ orig_len,
                   const float* __restrict__ fc_w,
                   const float* __restrict__ fc_b,
                   float* __restrict__ out) {
  const int tid  = threadIdx.x;        // 256
  const int pair = tid >> 2;           // (b,n)
  const int part = tid & 3;
  const int b = pair >> 1;
  const int n = pair & 1;
  const int L = orig_len[b] - 20;
  const int kern2 = L - (L >> 1);
  const u32* fb = featU + (size_t)b * 384;
  const float* ff = (const float*)fb;
  float acc = 0.f;
  for (int j = part; j < 384; j += 4) {
    float fv;
    if (j < 192)      fv = decf(fb[j]);
    else if (j < 256) fv = ff[j] / (float)L;
    else              fv = ff[j] / (float)kern2;
    acc += fv * fc_w[n * 384 + j];
  }
  acc += __shfl_xor(acc, 1, 64);
  acc += __shfl_xor(acc, 2, 64);
  if (part == 0) out[b * 2 + n] = acc + fc_b[n];
}

// ---------------------------------------------------------------------------
extern "C" void kernel_launch(void* const* d_in, const int* in_sizes, int n_in,
                              void* d_out, int out_size, void* d_ws, size_t ws_size,
                              hipStream_t stream) {
  const float* x        = (const float*)d_in[0];
  const int*   orig_len = (const int*)d_in[1];
  const float* w1  = (const float*)d_in[2];
  const float* g1  = (const float*)d_in[3];
  const float* b1  = (const float*)d_in[4];
  const float* w2  = (const float*)d_in[5];
  const float* g2  = (const float*)d_in[6];
  const float* b2  = (const float*)d_in[7];
  const float* fcw = (const float*)d_in[8];
  const float* fcb = (const float*)d_in[9];
  float* out = (float*)d_out;

  char* ws = (char*)d_ws;
  const size_t XT_BYTES = (size_t)Bn * TPAD * 64 * 2;    // 67,239,936
  const size_t Y_BYTES  = (size_t)Bn * Tn * 64 * 2;      // 67,108,864
  const size_t WF_BYTES = (size_t)42 * 4 * 64 * 8 * 2;   // 172,032
  size_t off = 0;
  u16* x_t = (u16*)(ws + off); off += XT_BYTES;
  u16* y1  = (u16*)(ws + off); off += Y_BYTES;
  u16* y2  = (u16*)(ws + off); off += Y_BYTES;
  u16* wf1 = (u16*)(ws + off); off += WF_BYTES;
  u16* wf2 = (u16*)(ws + off); off += WF_BYTES;
  float* stats = (float*)(ws + off);                 // 1024 B (2cv x 64co x {s,sq})
  u32*   featU = (u32*)(ws + off + 1024);            // 32*384*4 = 49152 B
  const size_t SMALL_BYTES = 1024 + 49152;

  hipMemsetAsync(ws + off, 0, SMALL_BYTES, stream);
  transpose_x<<<Bn * 256 + 84, 256, 0, stream>>>(x, x_t, w1, w2, wf1, wf2);
  conv_mfma<<<Bn * 64 * 2, 256, 0, stream>>>(x_t, wf1, wf2, y1, y2, stats);
  spp<<<Bn * 16, 256, 0, stream>>>(y1, y2, stats, g1, b1, g2, b2, orig_len, featU);
  fc<<<1, 256, 0, stream>>>(featU, orig_len, fcw, fcb, out);
  (void)in_sizes; (void)n_in; (void)out_size; (void)ws_size;
}